// Round 11
// baseline (2196.294 us; speedup 1.0000x reference)
//
#include <hip/hip_runtime.h>
#include <stdint.h>

// ---------------------------------------------------------------------------
// Decoder_72516227826046 — R11: VALU trim of the dominant low_pre_kernel.
//  - U inner loop: rotation expressed as two sequential-h segments (same FP
//    accumulation order, sequential addresses -> no index/mask VALU).
//  - Gumbel table generation relocated into K1's dispatch (extra blocks),
//    overlapping the latency-bound high chain; K2a reads row 0 from ws.
// All FP op sequences bit-identical to the passing R10 kernel.
//  K1  (512+6144 blocks): high decode chain + gumbel tables -> ws.
//  K2a (6144x256): per-(b,ci) low precompute: step0 + U -> ws.
//  K2b (6144x64):  serial 39-step tail.   K3 (2x256): cell_reward link.
// ---------------------------------------------------------------------------

#define NB    512
#define NCELL 12
#define NNODE 40
#define EDIM  128
#define EDP   129
#define THREADS 256

#define OFF_CLP  0
#define OFF_NLP  512
#define OFF_CRW  6656
#define OFF_NRW  7168
#define OFF_CACT 13312
#define OFF_NACT 19456

// ws layout (float units)
#define WS_PTS_BASE   6144
#define WS_META_BASE  30720
#define WS_U_BASE     55296
#define WS_GUM_BASE   9885696
#define WS_TOTAL_F    19716096ull

// ---------------- threefry2x32 ----------------
__device__ __forceinline__ uint32_t rotl32(uint32_t x, int d) {
  return (x << d) | (x >> (32 - d));
}

__device__ __forceinline__ void tf2x32(uint32_t k0, uint32_t k1,
                                       uint32_t c0, uint32_t c1,
                                       uint32_t& o0, uint32_t& o1) {
  uint32_t ks2 = k0 ^ k1 ^ 0x1BD11BDAu;
  uint32_t x0 = c0 + k0, x1 = c1 + k1;
#define TFR(r) { x0 += x1; x1 = rotl32(x1, (r)); x1 ^= x0; }
  TFR(13) TFR(15) TFR(26) TFR(6)   x0 += k1;  x1 += ks2 + 1u;
  TFR(17) TFR(29) TFR(16) TFR(24)  x0 += ks2; x1 += k0 + 2u;
  TFR(13) TFR(15) TFR(26) TFR(6)   x0 += k0;  x1 += k1 + 3u;
  TFR(17) TFR(29) TFR(16) TFR(24)  x0 += k1;  x1 += ks2 + 4u;
  TFR(13) TFR(15) TFR(26) TFR(6)   x0 += ks2; x1 += k0 + 5u;
#undef TFR
  o0 = x0; o1 = x1;
}

__device__ __forceinline__ uint32_t draw_bits(uint32_t k0, uint32_t k1,
                                              uint32_t idx) {
  uint32_t o0, o1;
  tf2x32(k0, k1, 0u, idx, o0, o1);
  return o0 ^ o1;
}

__device__ __forceinline__ float bits_to_gumbel(uint32_t bits) {
  uint32_t fb = (bits >> 9) | 0x3F800000u;
  float f = __uint_as_float(fb) - 1.0f;
  const float TINY = 1.17549435082228751e-38f;
  float u = f * (1.0f - TINY) + TINY;
  u = fmaxf(TINY, u);
  return -logf(-logf(u));
}

__device__ __forceinline__ float xla_tanh(float x) {
#pragma clang fp contract(off)
  float ax = fabsf(x);
  float xc = fminf(fmaxf(x, -9.0f), 9.0f);
  float x2 = xc * xc;
  float nm = -2.76076847742355e-16f;
  nm = nm * x2 + 2.00018790482477e-13f;
  nm = nm * x2 + -8.60467152213735e-11f;
  nm = nm * x2 + 5.12229709037114e-08f;
  nm = nm * x2 + 1.48572235717979e-05f;
  nm = nm * x2 + 6.37261928875436e-04f;
  nm = nm * x2 + 4.89352455891786e-03f;
  nm = xc * nm;
  float dn = 1.19825839466702e-06f;
  dn = dn * x2 + 1.18534705686654e-04f;
  dn = dn * x2 + 2.26843463243900e-03f;
  dn = dn * x2 + 4.89352518554385e-03f;
  return (ax < 0.0004f) ? x : (nm / dn);
}

template<int KLEN>
__device__ __forceinline__ void matvec(const float* __restrict__ W,
                                       const float* __restrict__ src,
                                       const float* __restrict__ pre,
                                       const float* __restrict__ bias,
                                       float* dest, float* part, int t) {
  const int j  = t & 127;
  const int hv = t >> 7;
  const int kh = KLEN / 2;
  const int k0 = hv * kh;
  float acc = 0.f;
  const float* Wp = W + (size_t)k0 * EDIM + j;
  const float* sp = src + k0;
#pragma unroll 8
  for (int k = 0; k < kh; ++k) acc = fmaf(sp[k], Wp[(size_t)k * EDIM], acc);
  if (hv) part[j] = acc;
  __syncthreads();
  if (!hv) {
    float r = acc + part[j];
    if (pre)  r += pre[j];
    if (bias) r += bias[j];
    dest[j] = r;
  }
  __syncthreads();
}

template<int RPH, int SSTR, int DSTR>
__device__ __forceinline__ void computeK(const float* __restrict__ W,
                                         const float* __restrict__ bias,
                                         const float* src, float* dst, int t) {
  const int j  = t & 127;
  const int hv = t >> 7;
  float acc[RPH];
#pragma unroll
  for (int s = 0; s < RPH; ++s) acc[s] = 0.f;
  const float* Wp = W + j;
#pragma unroll 4
  for (int k = 0; k < EDIM; ++k) {
    float w = Wp[(size_t)k * EDIM];
#pragma unroll
    for (int s = 0; s < RPH; ++s)
      acc[s] = fmaf(src[(hv + 2 * s) * SSTR + k], w, acc[s]);
  }
  float bj = bias[j];
#pragma unroll
  for (int s = 0; s < RPH; ++s) dst[(hv + 2 * s) * DSTR + j] = acc[s] + bj;
}

// ========== K1: high decode (blocks < NB) + gumbel tables (blocks >= NB) ====
__global__ __launch_bounds__(THREADS, 2)
void high_kernel(const float* __restrict__ cell_context,
                 const float* __restrict__ high_mask,
                 const float* __restrict__ init_w,
                 const float* __restrict__ W_hc,  const float* __restrict__ b_hc,
                 const float* __restrict__ W_vw,  const float* __restrict__ b_vw,
                 const float* __restrict__ Wq,    const float* __restrict__ bq,
                 const float* __restrict__ Wk,    const float* __restrict__ bk,
                 const float* __restrict__ v_hi,
                 float* __restrict__ out, int* __restrict__ ws_cidx,
                 float* __restrict__ ws_gum) {
  const int t = threadIdx.x;

  __shared__ float s_cc[NCELL][EDIM];
  __shared__ float s_Kh[NCELL][EDIM];
  __shared__ float s_ghum[NCELL * NCELL];
  __shared__ float s_qh[EDIM], s_qq[EDIM], s_qbh[EDIM], s_hbh[EDIM];
  __shared__ float s_mean[EDIM], s_part[EDIM];
  __shared__ float s_vh[EDIM], s_bqh[EDIM];
  __shared__ float s_iw[2 * EDIM];
  __shared__ float s_u[NCELL];
  __shared__ float s_maskh[NCELL];
  __shared__ uint32_t s_kh[NCELL][2];
  __shared__ uint32_t s_base[2];
  __shared__ uint32_t g_ks[NNODE][2];
  __shared__ int s_idx;

  // ---- gumbel blocks: fill ws_gum for bc = blockIdx - NB ----
  if (blockIdx.x >= NB) {
    const int bc = blockIdx.x - NB;
    const int b  = bc / NCELL;
    const int ci = bc - b * NCELL;
    uint32_t a0, a1, c0, c1;
    tf2x32(0u, 42u, 0u, 1u, a0, a1);                 // fold_in(root, 1)
    tf2x32(a0, a1, 0u, (uint32_t)ci, c0, c1);        // split -> cell key
    if (t < NNODE)
      tf2x32(c0, c1, 0u, (uint32_t)t, g_ks[t][0], g_ks[t][1]);
    __syncthreads();
    float* gg = ws_gum + (size_t)bc * (NNODE * NNODE);
    for (int g = t; g < NNODE * NNODE; g += THREADS) {
      int st = g / NNODE, n = g - st * NNODE;
      gg[g] = bits_to_gumbel(draw_bits(g_ks[st][0], g_ks[st][1],
                                       (uint32_t)(b * NNODE + n)));
    }
    return;
  }

  const int b = blockIdx.x;

  if (t == 0) {
    uint32_t a0, a1;
    tf2x32(0u, 42u, 0u, 0u, a0, a1); s_base[0] = a0; s_base[1] = a1;
  }
  __syncthreads();
  if (t < NCELL)
    tf2x32(s_base[0], s_base[1], 0u, (uint32_t)t, s_kh[t][0], s_kh[t][1]);

  if (t < EDIM) { s_vh[t] = v_hi[t]; s_bqh[t] = bq[t]; }
  s_iw[t] = init_w[t];
  if (t < NCELL) s_maskh[t] = high_mask[b * NCELL + t];

  if (t < EDIM) {
    float s = 0.f;
    for (int n = 0; n < NCELL; ++n) {
      float x = cell_context[((size_t)b * NCELL + n) * EDIM + t];
      s_cc[n][t] = x; s += x;
    }
    s_mean[t] = s / 12.0f;
  }
  __syncthreads();
  if (t < NCELL * NCELL) {
    int ci = t / NCELL, n = t - ci * NCELL;
    s_ghum[t] = bits_to_gumbel(draw_bits(s_kh[ci][0], s_kh[ci][1],
                                         (uint32_t)(b * NCELL + n)));
  }
  matvec<128>(W_hc, s_mean, nullptr, b_hc, s_hbh, s_part, t);
  computeK<6, EDIM, EDIM>(Wk, bk, &s_cc[0][0], &s_Kh[0][0], t);
  __syncthreads();
  matvec<256>(W_vw, s_iw, s_hbh, b_vw, s_qh, s_part, t);
  if (t < EDIM) s_qbh[t] = s_hbh[t] + b_vw[t];
  __syncthreads();

  float cell_lp = 0.f;

  for (int ci = 0; ci < NCELL; ++ci) {
    matvec<128>(Wq, s_qh, nullptr, s_bqh, s_qq, s_part, t);
    if (t < 4 * NCELL) {
      int nd = t >> 2, p = t & 3, rot = t & 31;
      float acc = 0.f;
#pragma unroll 4
      for (int i2 = 0; i2 < 32; ++i2) {
        int h = p * 32 + ((i2 + rot) & 31);
        acc = fmaf(s_vh[h], xla_tanh(s_qq[h] + s_Kh[nd][h]), acc);
      }
      acc += __shfl_xor(acc, 1);
      acc += __shfl_xor(acc, 2);
      if (p == 0) s_u[nd] = acc;
    }
    __syncthreads();

    if (t < 64) {
      float logit = -__builtin_huge_valf(), val = -__builtin_huge_valf();
      if (t < NCELL) {
        float lg = (s_maskh[t] > 0.f) ? -1e9f : 10.0f * xla_tanh(s_u[t]);
        logit = lg;
        val = lg + s_ghum[ci * NCELL + t];
      }
      int bidx = t;
      float mx = logit;
#pragma unroll
      for (int d = 32; d; d >>= 1) {
        float oval = __shfl_xor(val, d);
        int   oidx = __shfl_xor(bidx, d);
        float omx  = __shfl_xor(mx, d);
        if (oval > val || (oval == val && oidx < bidx)) { val = oval; bidx = oidx; }
        mx = fmaxf(mx, omx);
      }
      float ex = (t < NCELL) ? expf(logit - mx) : 0.f;
#pragma unroll
      for (int d = 32; d; d >>= 1) ex += __shfl_xor(ex, d);
      float chosen = __shfl(logit, bidx);
      cell_lp += (chosen - mx) - logf(ex);
      if (t == 0) {
        s_idx = bidx;
        s_maskh[bidx] = 1.0f;
        out[OFF_CACT + b * NCELL + ci] = (float)bidx;
        ws_cidx[b * NCELL + ci] = bidx;
      }
    }
    __syncthreads();
    const int cidx = s_idx;

    if (ci == 0)
      matvec<128>(W_vw, &s_cc[cidx][0], s_qbh, nullptr, s_qbh, s_part, t);
    if (ci < NCELL - 1)
      matvec<128>(W_vw + 128 * EDIM, &s_cc[cidx][0], s_qbh, nullptr, s_qh, s_part, t);
  }

  if (t == 0) out[OFF_CLP + b] = cell_lp;
}

// ============== K2a: low precompute (step0 + U -> ws) ============
__global__ __launch_bounds__(THREADS, 3)
void low_pre_kernel(const float* __restrict__ node_context,
                    const float* __restrict__ original_data,
                    const float* __restrict__ low_mask,
                    const float* __restrict__ low_init_w,
                    const float* __restrict__ low_W_hc, const float* __restrict__ low_b_hc,
                    const float* __restrict__ low_W_vw, const float* __restrict__ low_b_vw,
                    const float* __restrict__ low_Wq,   const float* __restrict__ low_bq,
                    const float* __restrict__ low_Wk,   const float* __restrict__ low_bk,
                    const float* __restrict__ v_lo,
                    const int* __restrict__ ws_cidx,
                    float* __restrict__ ws_meta,
                    float* __restrict__ ws_U,
                    const float* __restrict__ ws_gum,
                    float* __restrict__ out) {
  const int bc = blockIdx.x;
  const int b  = bc / NCELL;
  const int t  = threadIdx.x;
  const int j  = t & 127;
  const int hv = t >> 7;

  __shared__ float s_eq[NNODE * EDP];
  __shared__ float s_Kl[NNODE * EDP];
  __shared__ float s_g0[NNODE];
  __shared__ float s_coords[NNODE][2];
  __shared__ float s_ql[EDIM], s_qq[EDIM], s_qbl[EDIM], s_hbl[EDIM];
  __shared__ float s_mean[EDIM], s_part[EDIM];
  __shared__ float s_vl[EDIM], s_bql[EDIM];
  __shared__ float s_iwl[2 * EDIM];
  __shared__ float s_u[NNODE];
  __shared__ float s_maskl[NNODE];
  __shared__ int s_cidx;
  __shared__ int s_idx;

  if (t == 0) s_cidx = ws_cidx[bc];
  __syncthreads();
  const int cidx = s_cidx;

  if (t < EDIM) { s_vl[t] = v_lo[t]; s_bql[t] = low_bq[t]; }
  s_iwl[t] = low_init_w[t];
  if (t < NNODE) s_g0[t] = ws_gum[(size_t)bc * (NNODE * NNODE) + t];

  const float* embg = node_context + (((size_t)b * NCELL + cidx) * NNODE) * EDIM;
  if (t < EDIM) {
    float s = 0.f;
    for (int n = 0; n < NNODE; ++n) {
      float x = embg[n * EDIM + t];
      s_eq[n * EDP + t] = x; s += x;
    }
    s_mean[t] = s / 40.0f;
  }
  if (t >= 128 && t < 208) {
    int q = t - 128;
    s_coords[q >> 1][q & 1] = original_data[(((size_t)b * NCELL + cidx) * NNODE) * 2 + q];
  }
  if (t >= 208 && t < 208 + NNODE) s_maskl[t - 208] = low_mask[b * NNODE + (t - 208)];
  __syncthreads();

  matvec<128>(low_W_hc, s_mean, nullptr, low_b_hc, s_hbl, s_part, t);
  computeK<20, EDP, EDP>(low_Wk, low_bk, &s_eq[0], &s_Kl[0], t);

  {
    float accA[20], accB[20];
#pragma unroll
    for (int s = 0; s < 20; ++s) { accA[s] = 0.f; accB[s] = 0.f; }
    const float* Wb = low_W_vw + (size_t)128 * EDIM + j;
#pragma unroll 2
    for (int k = 0; k < 64; ++k) {
      float w = Wb[(size_t)k * EDIM];
#pragma unroll
      for (int s = 0; s < 20; ++s)
        accA[s] = fmaf(s_eq[(hv + 2 * s) * EDP + k], w, accA[s]);
    }
#pragma unroll 2
    for (int k = 64; k < 128; ++k) {
      float w = Wb[(size_t)k * EDIM];
#pragma unroll
      for (int s = 0; s < 20; ++s)
        accB[s] = fmaf(s_eq[(hv + 2 * s) * EDP + k], w, accB[s]);
    }
    __syncthreads();
#pragma unroll
    for (int s = 0; s < 20; ++s)
      s_eq[(hv + 2 * s) * EDP + j] = accA[s] + accB[s];
  }
  matvec<256>(low_W_vw, s_iwl, s_hbl, low_b_vw, s_ql, s_part, t);
  if (t < EDIM) s_qbl[t] = s_hbl[t] + low_b_vw[t];
  __syncthreads();

  matvec<128>(low_Wq, s_ql, nullptr, s_bql, s_qq, s_part, t);
  if (t < 160) {
    int nd = t >> 2, p = t & 3, rot = t & 31;
    float acc = 0.f;
#pragma unroll 4
    for (int i2 = 0; i2 < 32; ++i2) {
      int h = p * 32 + ((i2 + rot) & 31);
      acc = fmaf(s_vl[h], xla_tanh(s_qq[h] + s_Kl[nd * EDP + h]), acc);
    }
    acc += __shfl_xor(acc, 1);
    acc += __shfl_xor(acc, 2);
    if (p == 0) s_u[nd] = acc;
  }
  __syncthreads();

  if (t < 64) {
    float maskreg = (t < NNODE) ? s_maskl[t] : 1.0f;
    float logit = -__builtin_huge_valf(), val = -__builtin_huge_valf();
    if (t < NNODE) {
      float lg = (maskreg > 0.f) ? -1e9f : 10.0f * xla_tanh(s_u[t]);
      logit = lg;
      val = lg + s_g0[t];
    }
    int bidx = t;
    float mx = logit;
#pragma unroll
    for (int d = 32; d; d >>= 1) {
      float oval = __shfl_xor(val, d);
      int   oidx = __shfl_xor(bidx, d);
      float omx  = __shfl_xor(mx, d);
      if (oval > val || (oval == val && oidx < bidx)) { val = oval; bidx = oidx; }
      mx = fmaxf(mx, omx);
    }
    float ex = (t < NNODE) ? expf(logit - mx) : 0.f;
#pragma unroll
    for (int d = 32; d; d >>= 1) ex += __shfl_xor(ex, d);
    float chosen = __shfl(logit, bidx);
    float lp0 = (chosen - mx) - logf(ex);
    if (t == 0) {
      s_idx = bidx;
      out[OFF_NACT + ((size_t)bc) * NNODE + 0] = (float)bidx;
      float4 m; m.x = s_coords[bidx][0]; m.y = s_coords[bidx][1];
      m.z = lp0; m.w = (float)bidx;
      reinterpret_cast<float4*>(ws_meta)[bc] = m;
    }
  }
  __syncthreads();

  {
    const int n0 = s_idx;
    matvec<128>(low_W_vw, embg + (size_t)n0 * EDIM, s_qbl, nullptr, s_qbl, s_part, t);
    for (int i = t; i < NNODE * EDIM; i += THREADS) {
      int n = i >> 7, k = i & 127;
      s_eq[n * EDP + k] = s_eq[n * EDP + k] + s_qbl[k];
    }
    __syncthreads();
    {
      float ac0[20], ac1[20];
#pragma unroll
      for (int s = 0; s < 20; ++s) { ac0[s] = 0.f; ac1[s] = 0.f; }
      const float* Wqp = low_Wq + (size_t)(hv * 64) * EDIM + j;
      const float* qlb = &s_eq[0] + hv * 64;
#pragma unroll 2
      for (int k = 0; k < 64; ++k) {
        float w = Wqp[(size_t)k * EDIM];
#pragma unroll
        for (int s = 0; s < 20; ++s)
          ac0[s] = fmaf(qlb[s * EDP + k], w, ac0[s]);
#pragma unroll
        for (int s = 0; s < 20; ++s)
          ac1[s] = fmaf(qlb[(20 + s) * EDP + k], w, ac1[s]);
      }
      __syncthreads();
      if (hv) {
#pragma unroll
        for (int s = 0; s < 20; ++s) {
          s_eq[s * EDP + j]        = ac0[s];
          s_eq[(20 + s) * EDP + j] = ac1[s];
        }
      }
      __syncthreads();
      if (!hv) {
#pragma unroll
        for (int s = 0; s < 20; ++s) {
          s_eq[s * EDP + j]        = (ac0[s] + s_eq[s * EDP + j])        + s_bql[j];
          s_eq[(20 + s) * EDP + j] = (ac1[s] + s_eq[(20 + s) * EDP + j]) + s_bql[j];
        }
      }
      __syncthreads();
    }
  }

  // U[prow][nd]: rotation as two sequential-h segments (identical FP order,
  // sequential addresses -> no per-h index/mask VALU)
  {
    float* wU = ws_U + (size_t)bc * (NNODE * NNODE);
    for (int e = t; e < NNODE * NNODE; e += THREADS) {
      int nd = e / NNODE, prow = e - nd * NNODE;
      const float* qr = &s_eq[prow * EDP];
      const float* kr = &s_Kl[nd * EDP];
      float S[4];
#pragma unroll
      for (int p = 0; p < 4; ++p) {
        const int rot = (4 * nd + p) & 31;
        const float* aq = qr + p * 32;
        const float* ak = kr + p * 32;
        const float* av = s_vl + p * 32;
        float a = 0.f;
#pragma unroll 4
        for (int h = rot; h < 32; ++h)
          a = fmaf(av[h], xla_tanh(aq[h] + ak[h]), a);
#pragma unroll 4
        for (int h = 0; h < rot; ++h)
          a = fmaf(av[h], xla_tanh(aq[h] + ak[h]), a);
        S[p] = a;
      }
      wU[prow * NNODE + nd] = (S[0] + S[1]) + (S[2] + S[3]);
    }
  }
}

// ============== K2b: serial tail, one 64-thread block per (b,ci) ===========
__global__ __launch_bounds__(64)
void low_tail_kernel(const float* __restrict__ original_data,
                     const float* __restrict__ low_mask,
                     const int* __restrict__ ws_cidx,
                     const float* __restrict__ ws_meta,
                     const float* __restrict__ ws_U,
                     const float* __restrict__ ws_gum,
                     float* __restrict__ ws_pts,
                     float* __restrict__ out) {
  const int bc = blockIdx.x;
  const int b  = bc / NCELL;
  const int t  = threadIdx.x;

  __shared__ float sU[NNODE * NNODE];
  __shared__ float sG[NNODE * NNODE];
  __shared__ float sc[NNODE][2];
  __shared__ int s_cidx;

  if (t == 0) s_cidx = ws_cidx[bc];
  __syncthreads();
  const int cidx = s_cidx;

  {
    const float4* u4 = reinterpret_cast<const float4*>(ws_U + (size_t)bc * 1600);
    const float4* g4 = reinterpret_cast<const float4*>(ws_gum + (size_t)bc * 1600);
    float4* su4 = reinterpret_cast<float4*>(sU);
    float4* sg4 = reinterpret_cast<float4*>(sG);
    for (int i = t; i < 400; i += 64) { su4[i] = u4[i]; sg4[i] = g4[i]; }
    for (int q = t; q < 80; q += 64)
      sc[q >> 1][q & 1] = original_data[(((size_t)b * NCELL + cidx) * NNODE) * 2 + q];
  }
  float4 meta = reinterpret_cast<const float4*>(ws_meta)[bc];
  int   prev  = (int)meta.w;
  float initx = meta.x, inity = meta.y;
  float llp   = meta.z;
  float prevx = initx, prevy = inity, rew = 0.f;
  float maskreg = (t < NNODE) ? low_mask[b * NNODE + t] : 1.0f;
  if (t == prev) maskreg = 1.0f;
  __syncthreads();

  for (int st = 1; st < NNODE; ++st) {
    float logit = -__builtin_huge_valf(), val = -__builtin_huge_valf();
    if (t < NNODE) {
      float lg = (maskreg > 0.f) ? -1e9f : 10.0f * xla_tanh(sU[prev * NNODE + t]);
      logit = lg;
      val = lg + sG[st * NNODE + t];
    }
    int bidx = t;
    float mx = logit;
#pragma unroll
    for (int d = 32; d; d >>= 1) {
      float oval = __shfl_xor(val, d);
      int   oidx = __shfl_xor(bidx, d);
      float omx  = __shfl_xor(mx, d);
      if (oval > val || (oval == val && oidx < bidx)) { val = oval; bidx = oidx; }
      mx = fmaxf(mx, omx);
    }
    float ex = (t < NNODE) ? expf(logit - mx) : 0.f;
#pragma unroll
    for (int d = 32; d; d >>= 1) ex += __shfl_xor(ex, d);
    float chosen = __shfl(logit, bidx);
    llp += (chosen - mx) - logf(ex);
    float cx = sc[bidx][0], cy = sc[bidx][1];
    { float dx = cx - prevx, dy = cy - prevy; rew += sqrtf(dx * dx + dy * dy); }
    prevx = cx; prevy = cy;
    if (t == bidx) maskreg = 1.0f;
    prev = bidx;
    if (t == 0)
      out[OFF_NACT + ((size_t)bc) * NNODE + st] = (float)bidx;
  }
  if (t == 0) {
    out[OFF_NLP + bc] = llp;
    out[OFF_NRW + bc] = rew;
    float* p = ws_pts + (size_t)bc * 4;
    p[0] = initx; p[1] = inity; p[2] = prevx; p[3] = prevy;
  }
}

// ======== fallback: R8 fused low kernel (used if ws too small) =============
__global__ __launch_bounds__(THREADS, 2)
void low_kernel_fused(const float* __restrict__ node_context,
                      const float* __restrict__ original_data,
                      const float* __restrict__ low_mask,
                      const float* __restrict__ low_init_w,
                      const float* __restrict__ low_W_hc, const float* __restrict__ low_b_hc,
                      const float* __restrict__ low_W_vw, const float* __restrict__ low_b_vw,
                      const float* __restrict__ low_Wq,   const float* __restrict__ low_bq,
                      const float* __restrict__ low_Wk,   const float* __restrict__ low_bk,
                      const float* __restrict__ v_lo,
                      const int* __restrict__ ws_cidx,
                      float* __restrict__ ws_pts,
                      float* __restrict__ out) {
  const int bc = blockIdx.x;
  const int b  = bc / NCELL;
  const int ci = bc - b * NCELL;
  const int t  = threadIdx.x;
  const int j  = t & 127;
  const int hv = t >> 7;

  __shared__ float s_eq[NNODE * EDP];
  __shared__ float s_Kl[NNODE * EDP];
  __shared__ float s_U[NNODE * NNODE];
  __shared__ float s_gum[NNODE * NNODE];
  __shared__ float s_coords[NNODE][2];
  __shared__ float s_ql[EDIM], s_qq[EDIM], s_qbl[EDIM], s_hbl[EDIM];
  __shared__ float s_mean[EDIM], s_part[EDIM];
  __shared__ float s_vl[EDIM], s_bql[EDIM];
  __shared__ float s_iwl[2 * EDIM];
  __shared__ float s_u[NNODE];
  __shared__ float s_maskl[NNODE];
  __shared__ uint32_t s_ks[NNODE][2];
  __shared__ uint32_t s_kk[2];
  __shared__ int s_cidx;
  __shared__ int s_idx;

  if (t == 0) {
    uint32_t a0, a1, c0, c1;
    tf2x32(0u, 42u, 0u, 1u, a0, a1);
    tf2x32(a0, a1, 0u, (uint32_t)ci, c0, c1);
    s_kk[0] = c0; s_kk[1] = c1;
    s_cidx = ws_cidx[bc];
  }
  __syncthreads();
  const int cidx = s_cidx;

  if (t < EDIM) { s_vl[t] = v_lo[t]; s_bql[t] = low_bq[t]; }
  s_iwl[t] = low_init_w[t];
  if (t < NNODE)
    tf2x32(s_kk[0], s_kk[1], 0u, (uint32_t)t, s_ks[t][0], s_ks[t][1]);

  const float* embg = node_context + (((size_t)b * NCELL + cidx) * NNODE) * EDIM;
  if (t < EDIM) {
    float s = 0.f;
    for (int n = 0; n < NNODE; ++n) {
      float x = embg[n * EDIM + t];
      s_eq[n * EDP + t] = x; s += x;
    }
    s_mean[t] = s / 40.0f;
  }
  if (t >= 128 && t < 208) {
    int q = t - 128;
    s_coords[q >> 1][q & 1] = original_data[(((size_t)b * NCELL + cidx) * NNODE) * 2 + q];
  }
  if (t >= 208 && t < 208 + NNODE) s_maskl[t - 208] = low_mask[b * NNODE + (t - 208)];
  __syncthreads();

  for (int g = t; g < NNODE * NNODE; g += THREADS) {
    int st = g / NNODE, n = g - st * NNODE;
    s_gum[g] = bits_to_gumbel(draw_bits(s_ks[st][0], s_ks[st][1],
                                        (uint32_t)(b * NNODE + n)));
  }
  matvec<128>(low_W_hc, s_mean, nullptr, low_b_hc, s_hbl, s_part, t);
  computeK<20, EDP, EDP>(low_Wk, low_bk, &s_eq[0], &s_Kl[0], t);

  {
    float accA[20], accB[20];
#pragma unroll
    for (int s = 0; s < 20; ++s) { accA[s] = 0.f; accB[s] = 0.f; }
    const float* Wb = low_W_vw + (size_t)128 * EDIM + j;
#pragma unroll 2
    for (int k = 0; k < 64; ++k) {
      float w = Wb[(size_t)k * EDIM];
#pragma unroll
      for (int s = 0; s < 20; ++s)
        accA[s] = fmaf(s_eq[(hv + 2 * s) * EDP + k], w, accA[s]);
    }
#pragma unroll 2
    for (int k = 64; k < 128; ++k) {
      float w = Wb[(size_t)k * EDIM];
#pragma unroll
      for (int s = 0; s < 20; ++s)
        accB[s] = fmaf(s_eq[(hv + 2 * s) * EDP + k], w, accB[s]);
    }
    __syncthreads();
#pragma unroll
    for (int s = 0; s < 20; ++s)
      s_eq[(hv + 2 * s) * EDP + j] = accA[s] + accB[s];
  }
  matvec<256>(low_W_vw, s_iwl, s_hbl, low_b_vw, s_ql, s_part, t);
  if (t < EDIM) s_qbl[t] = s_hbl[t] + low_b_vw[t];
  __syncthreads();

  matvec<128>(low_Wq, s_ql, nullptr, s_bql, s_qq, s_part, t);
  if (t < 160) {
    int nd = t >> 2, p = t & 3, rot = t & 31;
    float acc = 0.f;
#pragma unroll 4
    for (int i2 = 0; i2 < 32; ++i2) {
      int h = p * 32 + ((i2 + rot) & 31);
      acc = fmaf(s_vl[h], xla_tanh(s_qq[h] + s_Kl[nd * EDP + h]), acc);
    }
    acc += __shfl_xor(acc, 1);
    acc += __shfl_xor(acc, 2);
    if (p == 0) s_u[nd] = acc;
  }
  __syncthreads();

  float llp = 0.f, rew = 0.f, prevx = 0.f, prevy = 0.f, initx = 0.f, inity = 0.f;
  float maskreg = 1.0f;
  int prev = 0;
  if (t < 64) {
    maskreg = (t < NNODE) ? s_maskl[t] : 1.0f;
    float logit = -__builtin_huge_valf(), val = -__builtin_huge_valf();
    if (t < NNODE) {
      float lg = (maskreg > 0.f) ? -1e9f : 10.0f * xla_tanh(s_u[t]);
      logit = lg;
      val = lg + s_gum[t];
    }
    int bidx = t;
    float mx = logit;
#pragma unroll
    for (int d = 32; d; d >>= 1) {
      float oval = __shfl_xor(val, d);
      int   oidx = __shfl_xor(bidx, d);
      float omx  = __shfl_xor(mx, d);
      if (oval > val || (oval == val && oidx < bidx)) { val = oval; bidx = oidx; }
      mx = fmaxf(mx, omx);
    }
    float ex = (t < NNODE) ? expf(logit - mx) : 0.f;
#pragma unroll
    for (int d = 32; d; d >>= 1) ex += __shfl_xor(ex, d);
    float chosen = __shfl(logit, bidx);
    llp += (chosen - mx) - logf(ex);
    initx = s_coords[bidx][0]; inity = s_coords[bidx][1];
    prevx = initx; prevy = inity;
    if (t == bidx) maskreg = 1.0f;
    prev = bidx;
    if (t == 0) {
      s_idx = bidx;
      out[OFF_NACT + ((size_t)bc) * NNODE + 0] = (float)bidx;
    }
  }
  __syncthreads();

  {
    const int n0 = s_idx;
    matvec<128>(low_W_vw, embg + (size_t)n0 * EDIM, s_qbl, nullptr, s_qbl, s_part, t);
    for (int i = t; i < NNODE * EDIM; i += THREADS) {
      int n = i >> 7, k = i & 127;
      s_eq[n * EDP + k] = s_eq[n * EDP + k] + s_qbl[k];
    }
    __syncthreads();
    {
      float ac0[20], ac1[20];
#pragma unroll
      for (int s = 0; s < 20; ++s) { ac0[s] = 0.f; ac1[s] = 0.f; }
      const float* Wqp = low_Wq + (size_t)(hv * 64) * EDIM + j;
      const float* qlb = &s_eq[0] + hv * 64;
#pragma unroll 2
      for (int k = 0; k < 64; ++k) {
        float w = Wqp[(size_t)k * EDIM];
#pragma unroll
        for (int s = 0; s < 20; ++s)
          ac0[s] = fmaf(qlb[s * EDP + k], w, ac0[s]);
#pragma unroll
        for (int s = 0; s < 20; ++s)
          ac1[s] = fmaf(qlb[(20 + s) * EDP + k], w, ac1[s]);
      }
      __syncthreads();
      if (hv) {
#pragma unroll
        for (int s = 0; s < 20; ++s) {
          s_eq[s * EDP + j]        = ac0[s];
          s_eq[(20 + s) * EDP + j] = ac1[s];
        }
      }
      __syncthreads();
      if (!hv) {
#pragma unroll
        for (int s = 0; s < 20; ++s) {
          s_eq[s * EDP + j]        = (ac0[s] + s_eq[s * EDP + j])        + s_bql[j];
          s_eq[(20 + s) * EDP + j] = (ac1[s] + s_eq[(20 + s) * EDP + j]) + s_bql[j];
        }
      }
      __syncthreads();
    }
  }

  for (int e = t; e < NNODE * NNODE; e += THREADS) {
    int nd = e / NNODE, prow = e - nd * NNODE;
    const float* qr = &s_eq[prow * EDP];
    const float* kr = &s_Kl[nd * EDP];
    float S[4];
#pragma unroll
    for (int p = 0; p < 4; ++p) {
      int rot = (4 * nd + p) & 31;
      float a = 0.f;
#pragma unroll 4
      for (int i2 = 0; i2 < 32; ++i2) {
        int h = p * 32 + ((i2 + rot) & 31);
        a = fmaf(s_vl[h], xla_tanh(qr[h] + kr[h]), a);
      }
      S[p] = a;
    }
    s_U[prow * NNODE + nd] = (S[0] + S[1]) + (S[2] + S[3]);
  }
  __syncthreads();

  if (t < 64) {
    for (int st = 1; st < NNODE; ++st) {
      float logit = -__builtin_huge_valf(), val = -__builtin_huge_valf();
      if (t < NNODE) {
        float lg = (maskreg > 0.f) ? -1e9f : 10.0f * xla_tanh(s_U[prev * NNODE + t]);
        logit = lg;
        val = lg + s_gum[st * NNODE + t];
      }
      int bidx = t;
      float mx = logit;
#pragma unroll
      for (int d = 32; d; d >>= 1) {
        float oval = __shfl_xor(val, d);
        int   oidx = __shfl_xor(bidx, d);
        float omx  = __shfl_xor(mx, d);
        if (oval > val || (oval == val && oidx < bidx)) { val = oval; bidx = oidx; }
        mx = fmaxf(mx, omx);
      }
      float ex = (t < NNODE) ? expf(logit - mx) : 0.f;
#pragma unroll
      for (int d = 32; d; d >>= 1) ex += __shfl_xor(ex, d);
      float chosen = __shfl(logit, bidx);
      llp += (chosen - mx) - logf(ex);
      float cx = s_coords[bidx][0], cy = s_coords[bidx][1];
      { float dx = cx - prevx, dy = cy - prevy; rew += sqrtf(dx * dx + dy * dy); }
      prevx = cx; prevy = cy;
      if (t == bidx) maskreg = 1.0f;
      prev = bidx;
      if (t == 0)
        out[OFF_NACT + ((size_t)bc) * NNODE + st] = (float)bidx;
    }
    if (t == 0) {
      out[OFF_NLP + bc] = llp;
      out[OFF_NRW + bc] = rew;
      float* p = ws_pts + (size_t)bc * 4;
      p[0] = initx; p[1] = inity; p[2] = prevx; p[3] = prevy;
    }
  }
}

// ======================= K3: cell_reward link =======================
__global__ void link_kernel(const float* __restrict__ ws_pts,
                            float* __restrict__ out) {
  int b = blockIdx.x * blockDim.x + threadIdx.x;
  if (b >= NB) return;
  float crew = 0.f;
  for (int ci = 1; ci < NCELL; ++ci) {
    const float* cur = ws_pts + (size_t)(b * NCELL + ci) * 4;
    const float* prv = ws_pts + (size_t)(b * NCELL + ci - 1) * 4;
    float dx = cur[0] - prv[2], dy = cur[1] - prv[3];
    crew += sqrtf(dx * dx + dy * dy);
  }
  out[OFF_CRW + b] = crew;
}

extern "C" void kernel_launch(void* const* d_in, const int* in_sizes, int n_in,
                              void* d_out, int out_size, void* d_ws, size_t ws_size,
                              hipStream_t stream) {
  (void)in_sizes; (void)n_in; (void)out_size;
  const float* node_context  = (const float*)d_in[0];
  const float* cell_context  = (const float*)d_in[1];
  const float* original_data = (const float*)d_in[2];
  const float* high_mask     = (const float*)d_in[3];
  const float* low_mask      = (const float*)d_in[4];
  const float* init_w        = (const float*)d_in[5];
  const float* W_hc  = (const float*)d_in[6];
  const float* b_hc  = (const float*)d_in[7];
  const float* W_vw  = (const float*)d_in[8];
  const float* b_vw  = (const float*)d_in[9];
  const float* Wq    = (const float*)d_in[10];
  const float* bq    = (const float*)d_in[11];
  const float* Wk    = (const float*)d_in[12];
  const float* bk    = (const float*)d_in[13];
  const float* v_hi  = (const float*)d_in[14];
  const float* low_init_w = (const float*)d_in[15];
  const float* low_W_hc   = (const float*)d_in[16];
  const float* low_b_hc   = (const float*)d_in[17];
  const float* low_W_vw   = (const float*)d_in[18];
  const float* low_b_vw   = (const float*)d_in[19];
  const float* low_Wq     = (const float*)d_in[20];
  const float* low_bq     = (const float*)d_in[21];
  const float* low_Wk     = (const float*)d_in[22];
  const float* low_bk     = (const float*)d_in[23];
  const float* v_lo       = (const float*)d_in[24];
  float* out = (float*)d_out;
  float* wsf = (float*)d_ws;
  int*   ws_cidx = (int*)d_ws;
  float* ws_pts  = wsf + WS_PTS_BASE;
  float* ws_meta = wsf + WS_META_BASE;
  float* ws_U    = wsf + WS_U_BASE;
  float* ws_gum  = wsf + WS_GUM_BASE;

  const bool big_ws = (ws_size >= WS_TOTAL_F * 4ull);

  high_kernel<<<big_ws ? (NB + NB * NCELL) : NB, THREADS, 0, stream>>>(
      cell_context, high_mask, init_w, W_hc, b_hc, W_vw, b_vw,
      Wq, bq, Wk, bk, v_hi, out, ws_cidx, ws_gum);

  if (big_ws) {
    low_pre_kernel<<<NB * NCELL, THREADS, 0, stream>>>(
        node_context, original_data, low_mask, low_init_w,
        low_W_hc, low_b_hc, low_W_vw, low_b_vw,
        low_Wq, low_bq, low_Wk, low_bk, v_lo,
        ws_cidx, ws_meta, ws_U, ws_gum, out);
    low_tail_kernel<<<NB * NCELL, 64, 0, stream>>>(
        original_data, low_mask, ws_cidx, ws_meta, ws_U, ws_gum, ws_pts, out);
  } else {
    low_kernel_fused<<<NB * NCELL, THREADS, 0, stream>>>(
        node_context, original_data, low_mask, low_init_w,
        low_W_hc, low_b_hc, low_W_vw, low_b_vw,
        low_Wq, low_bq, low_Wk, low_bk, v_lo,
        ws_cidx, ws_pts, out);
  }

  link_kernel<<<2, 256, 0, stream>>>(ws_pts, out);
}

// Round 12
// 2095.315 us; speedup vs baseline: 1.0482x; 1.0482x over previous
//
#include <hip/hip_runtime.h>
#include <stdint.h>

// ---------------------------------------------------------------------------
// Decoder_72516227826046 — R12: R10 architecture + (only) the gumbel
// relocation from R11. U-loop restored to R10's masked-rotation form (R11's
// variable-trip-count segments regressed). All FP orders = R10 (bit-stable).
//  K1  (512+6144 blocks): high decode chain + gumbel tables -> ws.
//  K2a (6144x256): per-(b,ci) low precompute: step0 + U -> ws.
//  K2b (6144x64):  serial 39-step tail.   K3 (2x256): cell_reward link.
// ---------------------------------------------------------------------------

#define NB    512
#define NCELL 12
#define NNODE 40
#define EDIM  128
#define EDP   129
#define THREADS 256

#define OFF_CLP  0
#define OFF_NLP  512
#define OFF_CRW  6656
#define OFF_NRW  7168
#define OFF_CACT 13312
#define OFF_NACT 19456

// ws layout (float units)
#define WS_PTS_BASE   6144
#define WS_META_BASE  30720
#define WS_U_BASE     55296
#define WS_GUM_BASE   9885696
#define WS_TOTAL_F    19716096ull

// ---------------- threefry2x32 ----------------
__device__ __forceinline__ uint32_t rotl32(uint32_t x, int d) {
  return (x << d) | (x >> (32 - d));
}

__device__ __forceinline__ void tf2x32(uint32_t k0, uint32_t k1,
                                       uint32_t c0, uint32_t c1,
                                       uint32_t& o0, uint32_t& o1) {
  uint32_t ks2 = k0 ^ k1 ^ 0x1BD11BDAu;
  uint32_t x0 = c0 + k0, x1 = c1 + k1;
#define TFR(r) { x0 += x1; x1 = rotl32(x1, (r)); x1 ^= x0; }
  TFR(13) TFR(15) TFR(26) TFR(6)   x0 += k1;  x1 += ks2 + 1u;
  TFR(17) TFR(29) TFR(16) TFR(24)  x0 += ks2; x1 += k0 + 2u;
  TFR(13) TFR(15) TFR(26) TFR(6)   x0 += k0;  x1 += k1 + 3u;
  TFR(17) TFR(29) TFR(16) TFR(24)  x0 += k1;  x1 += ks2 + 4u;
  TFR(13) TFR(15) TFR(26) TFR(6)   x0 += ks2; x1 += k0 + 5u;
#undef TFR
  o0 = x0; o1 = x1;
}

__device__ __forceinline__ uint32_t draw_bits(uint32_t k0, uint32_t k1,
                                              uint32_t idx) {
  uint32_t o0, o1;
  tf2x32(k0, k1, 0u, idx, o0, o1);
  return o0 ^ o1;
}

__device__ __forceinline__ float bits_to_gumbel(uint32_t bits) {
  uint32_t fb = (bits >> 9) | 0x3F800000u;
  float f = __uint_as_float(fb) - 1.0f;
  const float TINY = 1.17549435082228751e-38f;
  float u = f * (1.0f - TINY) + TINY;
  u = fmaxf(TINY, u);
  return -logf(-logf(u));
}

__device__ __forceinline__ float xla_tanh(float x) {
#pragma clang fp contract(off)
  float ax = fabsf(x);
  float xc = fminf(fmaxf(x, -9.0f), 9.0f);
  float x2 = xc * xc;
  float nm = -2.76076847742355e-16f;
  nm = nm * x2 + 2.00018790482477e-13f;
  nm = nm * x2 + -8.60467152213735e-11f;
  nm = nm * x2 + 5.12229709037114e-08f;
  nm = nm * x2 + 1.48572235717979e-05f;
  nm = nm * x2 + 6.37261928875436e-04f;
  nm = nm * x2 + 4.89352455891786e-03f;
  nm = xc * nm;
  float dn = 1.19825839466702e-06f;
  dn = dn * x2 + 1.18534705686654e-04f;
  dn = dn * x2 + 2.26843463243900e-03f;
  dn = dn * x2 + 4.89352518554385e-03f;
  return (ax < 0.0004f) ? x : (nm / dn);
}

template<int KLEN>
__device__ __forceinline__ void matvec(const float* __restrict__ W,
                                       const float* __restrict__ src,
                                       const float* __restrict__ pre,
                                       const float* __restrict__ bias,
                                       float* dest, float* part, int t) {
  const int j  = t & 127;
  const int hv = t >> 7;
  const int kh = KLEN / 2;
  const int k0 = hv * kh;
  float acc = 0.f;
  const float* Wp = W + (size_t)k0 * EDIM + j;
  const float* sp = src + k0;
#pragma unroll 8
  for (int k = 0; k < kh; ++k) acc = fmaf(sp[k], Wp[(size_t)k * EDIM], acc);
  if (hv) part[j] = acc;
  __syncthreads();
  if (!hv) {
    float r = acc + part[j];
    if (pre)  r += pre[j];
    if (bias) r += bias[j];
    dest[j] = r;
  }
  __syncthreads();
}

template<int RPH, int SSTR, int DSTR>
__device__ __forceinline__ void computeK(const float* __restrict__ W,
                                         const float* __restrict__ bias,
                                         const float* src, float* dst, int t) {
  const int j  = t & 127;
  const int hv = t >> 7;
  float acc[RPH];
#pragma unroll
  for (int s = 0; s < RPH; ++s) acc[s] = 0.f;
  const float* Wp = W + j;
#pragma unroll 4
  for (int k = 0; k < EDIM; ++k) {
    float w = Wp[(size_t)k * EDIM];
#pragma unroll
    for (int s = 0; s < RPH; ++s)
      acc[s] = fmaf(src[(hv + 2 * s) * SSTR + k], w, acc[s]);
  }
  float bj = bias[j];
#pragma unroll
  for (int s = 0; s < RPH; ++s) dst[(hv + 2 * s) * DSTR + j] = acc[s] + bj;
}

// ========== K1: high decode (blocks < NB) + gumbel tables (blocks >= NB) ====
__global__ __launch_bounds__(THREADS, 2)
void high_kernel(const float* __restrict__ cell_context,
                 const float* __restrict__ high_mask,
                 const float* __restrict__ init_w,
                 const float* __restrict__ W_hc,  const float* __restrict__ b_hc,
                 const float* __restrict__ W_vw,  const float* __restrict__ b_vw,
                 const float* __restrict__ Wq,    const float* __restrict__ bq,
                 const float* __restrict__ Wk,    const float* __restrict__ bk,
                 const float* __restrict__ v_hi,
                 float* __restrict__ out, int* __restrict__ ws_cidx,
                 float* __restrict__ ws_gum) {
  const int t = threadIdx.x;

  __shared__ float s_cc[NCELL][EDIM];
  __shared__ float s_Kh[NCELL][EDIM];
  __shared__ float s_ghum[NCELL * NCELL];
  __shared__ float s_qh[EDIM], s_qq[EDIM], s_qbh[EDIM], s_hbh[EDIM];
  __shared__ float s_mean[EDIM], s_part[EDIM];
  __shared__ float s_vh[EDIM], s_bqh[EDIM];
  __shared__ float s_iw[2 * EDIM];
  __shared__ float s_u[NCELL];
  __shared__ float s_maskh[NCELL];
  __shared__ uint32_t s_kh[NCELL][2];
  __shared__ uint32_t s_base[2];
  __shared__ uint32_t g_ks[NNODE][2];
  __shared__ int s_idx;

  if (blockIdx.x >= NB) {      // gumbel table blocks
    const int bc = blockIdx.x - NB;
    const int b  = bc / NCELL;
    const int ci = bc - b * NCELL;
    uint32_t a0, a1, c0, c1;
    tf2x32(0u, 42u, 0u, 1u, a0, a1);                 // fold_in(root, 1)
    tf2x32(a0, a1, 0u, (uint32_t)ci, c0, c1);        // split -> cell key
    if (t < NNODE)
      tf2x32(c0, c1, 0u, (uint32_t)t, g_ks[t][0], g_ks[t][1]);
    __syncthreads();
    float* gg = ws_gum + (size_t)bc * (NNODE * NNODE);
    for (int g = t; g < NNODE * NNODE; g += THREADS) {
      int st = g / NNODE, n = g - st * NNODE;
      gg[g] = bits_to_gumbel(draw_bits(g_ks[st][0], g_ks[st][1],
                                       (uint32_t)(b * NNODE + n)));
    }
    return;
  }

  const int b = blockIdx.x;

  if (t == 0) {
    uint32_t a0, a1;
    tf2x32(0u, 42u, 0u, 0u, a0, a1); s_base[0] = a0; s_base[1] = a1;
  }
  __syncthreads();
  if (t < NCELL)
    tf2x32(s_base[0], s_base[1], 0u, (uint32_t)t, s_kh[t][0], s_kh[t][1]);

  if (t < EDIM) { s_vh[t] = v_hi[t]; s_bqh[t] = bq[t]; }
  s_iw[t] = init_w[t];
  if (t < NCELL) s_maskh[t] = high_mask[b * NCELL + t];

  if (t < EDIM) {
    float s = 0.f;
    for (int n = 0; n < NCELL; ++n) {
      float x = cell_context[((size_t)b * NCELL + n) * EDIM + t];
      s_cc[n][t] = x; s += x;
    }
    s_mean[t] = s / 12.0f;
  }
  __syncthreads();
  if (t < NCELL * NCELL) {
    int ci = t / NCELL, n = t - ci * NCELL;
    s_ghum[t] = bits_to_gumbel(draw_bits(s_kh[ci][0], s_kh[ci][1],
                                         (uint32_t)(b * NCELL + n)));
  }
  matvec<128>(W_hc, s_mean, nullptr, b_hc, s_hbh, s_part, t);
  computeK<6, EDIM, EDIM>(Wk, bk, &s_cc[0][0], &s_Kh[0][0], t);
  __syncthreads();
  matvec<256>(W_vw, s_iw, s_hbh, b_vw, s_qh, s_part, t);
  if (t < EDIM) s_qbh[t] = s_hbh[t] + b_vw[t];
  __syncthreads();

  float cell_lp = 0.f;

  for (int ci = 0; ci < NCELL; ++ci) {
    matvec<128>(Wq, s_qh, nullptr, s_bqh, s_qq, s_part, t);
    if (t < 4 * NCELL) {
      int nd = t >> 2, p = t & 3, rot = t & 31;
      float acc = 0.f;
#pragma unroll 4
      for (int i2 = 0; i2 < 32; ++i2) {
        int h = p * 32 + ((i2 + rot) & 31);
        acc = fmaf(s_vh[h], xla_tanh(s_qq[h] + s_Kh[nd][h]), acc);
      }
      acc += __shfl_xor(acc, 1);
      acc += __shfl_xor(acc, 2);
      if (p == 0) s_u[nd] = acc;
    }
    __syncthreads();

    if (t < 64) {
      float logit = -__builtin_huge_valf(), val = -__builtin_huge_valf();
      if (t < NCELL) {
        float lg = (s_maskh[t] > 0.f) ? -1e9f : 10.0f * xla_tanh(s_u[t]);
        logit = lg;
        val = lg + s_ghum[ci * NCELL + t];
      }
      int bidx = t;
      float mx = logit;
#pragma unroll
      for (int d = 32; d; d >>= 1) {
        float oval = __shfl_xor(val, d);
        int   oidx = __shfl_xor(bidx, d);
        float omx  = __shfl_xor(mx, d);
        if (oval > val || (oval == val && oidx < bidx)) { val = oval; bidx = oidx; }
        mx = fmaxf(mx, omx);
      }
      float ex = (t < NCELL) ? expf(logit - mx) : 0.f;
#pragma unroll
      for (int d = 32; d; d >>= 1) ex += __shfl_xor(ex, d);
      float chosen = __shfl(logit, bidx);
      cell_lp += (chosen - mx) - logf(ex);
      if (t == 0) {
        s_idx = bidx;
        s_maskh[bidx] = 1.0f;
        out[OFF_CACT + b * NCELL + ci] = (float)bidx;
        ws_cidx[b * NCELL + ci] = bidx;
      }
    }
    __syncthreads();
    const int cidx = s_idx;

    if (ci == 0)
      matvec<128>(W_vw, &s_cc[cidx][0], s_qbh, nullptr, s_qbh, s_part, t);
    if (ci < NCELL - 1)
      matvec<128>(W_vw + 128 * EDIM, &s_cc[cidx][0], s_qbh, nullptr, s_qh, s_part, t);
  }

  if (t == 0) out[OFF_CLP + b] = cell_lp;
}

// ============== K2a: low precompute (step0 + U -> ws) ============
__global__ __launch_bounds__(THREADS, 3)
void low_pre_kernel(const float* __restrict__ node_context,
                    const float* __restrict__ original_data,
                    const float* __restrict__ low_mask,
                    const float* __restrict__ low_init_w,
                    const float* __restrict__ low_W_hc, const float* __restrict__ low_b_hc,
                    const float* __restrict__ low_W_vw, const float* __restrict__ low_b_vw,
                    const float* __restrict__ low_Wq,   const float* __restrict__ low_bq,
                    const float* __restrict__ low_Wk,   const float* __restrict__ low_bk,
                    const float* __restrict__ v_lo,
                    const int* __restrict__ ws_cidx,
                    float* __restrict__ ws_meta,
                    float* __restrict__ ws_U,
                    const float* __restrict__ ws_gum,
                    float* __restrict__ out) {
  const int bc = blockIdx.x;
  const int b  = bc / NCELL;
  const int t  = threadIdx.x;
  const int j  = t & 127;
  const int hv = t >> 7;

  __shared__ float s_eq[NNODE * EDP];
  __shared__ float s_Kl[NNODE * EDP];
  __shared__ float s_g0[NNODE];
  __shared__ float s_coords[NNODE][2];
  __shared__ float s_ql[EDIM], s_qq[EDIM], s_qbl[EDIM], s_hbl[EDIM];
  __shared__ float s_mean[EDIM], s_part[EDIM];
  __shared__ float s_vl[EDIM], s_bql[EDIM];
  __shared__ float s_iwl[2 * EDIM];
  __shared__ float s_u[NNODE];
  __shared__ float s_maskl[NNODE];
  __shared__ int s_cidx;
  __shared__ int s_idx;

  if (t == 0) s_cidx = ws_cidx[bc];
  __syncthreads();
  const int cidx = s_cidx;

  if (t < EDIM) { s_vl[t] = v_lo[t]; s_bql[t] = low_bq[t]; }
  s_iwl[t] = low_init_w[t];
  if (t < NNODE) s_g0[t] = ws_gum[(size_t)bc * (NNODE * NNODE) + t];

  const float* embg = node_context + (((size_t)b * NCELL + cidx) * NNODE) * EDIM;
  if (t < EDIM) {
    float s = 0.f;
    for (int n = 0; n < NNODE; ++n) {
      float x = embg[n * EDIM + t];
      s_eq[n * EDP + t] = x; s += x;
    }
    s_mean[t] = s / 40.0f;
  }
  if (t >= 128 && t < 208) {
    int q = t - 128;
    s_coords[q >> 1][q & 1] = original_data[(((size_t)b * NCELL + cidx) * NNODE) * 2 + q];
  }
  if (t >= 208 && t < 208 + NNODE) s_maskl[t - 208] = low_mask[b * NNODE + (t - 208)];
  __syncthreads();

  matvec<128>(low_W_hc, s_mean, nullptr, low_b_hc, s_hbl, s_part, t);
  computeK<20, EDP, EDP>(low_Wk, low_bk, &s_eq[0], &s_Kl[0], t);

  {
    float accA[20], accB[20];
#pragma unroll
    for (int s = 0; s < 20; ++s) { accA[s] = 0.f; accB[s] = 0.f; }
    const float* Wb = low_W_vw + (size_t)128 * EDIM + j;
#pragma unroll 2
    for (int k = 0; k < 64; ++k) {
      float w = Wb[(size_t)k * EDIM];
#pragma unroll
      for (int s = 0; s < 20; ++s)
        accA[s] = fmaf(s_eq[(hv + 2 * s) * EDP + k], w, accA[s]);
    }
#pragma unroll 2
    for (int k = 64; k < 128; ++k) {
      float w = Wb[(size_t)k * EDIM];
#pragma unroll
      for (int s = 0; s < 20; ++s)
        accB[s] = fmaf(s_eq[(hv + 2 * s) * EDP + k], w, accB[s]);
    }
    __syncthreads();
#pragma unroll
    for (int s = 0; s < 20; ++s)
      s_eq[(hv + 2 * s) * EDP + j] = accA[s] + accB[s];
  }
  matvec<256>(low_W_vw, s_iwl, s_hbl, low_b_vw, s_ql, s_part, t);
  if (t < EDIM) s_qbl[t] = s_hbl[t] + low_b_vw[t];
  __syncthreads();

  matvec<128>(low_Wq, s_ql, nullptr, s_bql, s_qq, s_part, t);
  if (t < 160) {
    int nd = t >> 2, p = t & 3, rot = t & 31;
    float acc = 0.f;
#pragma unroll 4
    for (int i2 = 0; i2 < 32; ++i2) {
      int h = p * 32 + ((i2 + rot) & 31);
      acc = fmaf(s_vl[h], xla_tanh(s_qq[h] + s_Kl[nd * EDP + h]), acc);
    }
    acc += __shfl_xor(acc, 1);
    acc += __shfl_xor(acc, 2);
    if (p == 0) s_u[nd] = acc;
  }
  __syncthreads();

  if (t < 64) {
    float maskreg = (t < NNODE) ? s_maskl[t] : 1.0f;
    float logit = -__builtin_huge_valf(), val = -__builtin_huge_valf();
    if (t < NNODE) {
      float lg = (maskreg > 0.f) ? -1e9f : 10.0f * xla_tanh(s_u[t]);
      logit = lg;
      val = lg + s_g0[t];
    }
    int bidx = t;
    float mx = logit;
#pragma unroll
    for (int d = 32; d; d >>= 1) {
      float oval = __shfl_xor(val, d);
      int   oidx = __shfl_xor(bidx, d);
      float omx  = __shfl_xor(mx, d);
      if (oval > val || (oval == val && oidx < bidx)) { val = oval; bidx = oidx; }
      mx = fmaxf(mx, omx);
    }
    float ex = (t < NNODE) ? expf(logit - mx) : 0.f;
#pragma unroll
    for (int d = 32; d; d >>= 1) ex += __shfl_xor(ex, d);
    float chosen = __shfl(logit, bidx);
    float lp0 = (chosen - mx) - logf(ex);
    if (t == 0) {
      s_idx = bidx;
      out[OFF_NACT + ((size_t)bc) * NNODE + 0] = (float)bidx;
      float4 m; m.x = s_coords[bidx][0]; m.y = s_coords[bidx][1];
      m.z = lp0; m.w = (float)bidx;
      reinterpret_cast<float4*>(ws_meta)[bc] = m;
    }
  }
  __syncthreads();

  {
    const int n0 = s_idx;
    matvec<128>(low_W_vw, embg + (size_t)n0 * EDIM, s_qbl, nullptr, s_qbl, s_part, t);
    for (int i = t; i < NNODE * EDIM; i += THREADS) {
      int n = i >> 7, k = i & 127;
      s_eq[n * EDP + k] = s_eq[n * EDP + k] + s_qbl[k];
    }
    __syncthreads();
    {
      float ac0[20], ac1[20];
#pragma unroll
      for (int s = 0; s < 20; ++s) { ac0[s] = 0.f; ac1[s] = 0.f; }
      const float* Wqp = low_Wq + (size_t)(hv * 64) * EDIM + j;
      const float* qlb = &s_eq[0] + hv * 64;
#pragma unroll 2
      for (int k = 0; k < 64; ++k) {
        float w = Wqp[(size_t)k * EDIM];
#pragma unroll
        for (int s = 0; s < 20; ++s)
          ac0[s] = fmaf(qlb[s * EDP + k], w, ac0[s]);
#pragma unroll
        for (int s = 0; s < 20; ++s)
          ac1[s] = fmaf(qlb[(20 + s) * EDP + k], w, ac1[s]);
      }
      __syncthreads();
      if (hv) {
#pragma unroll
        for (int s = 0; s < 20; ++s) {
          s_eq[s * EDP + j]        = ac0[s];
          s_eq[(20 + s) * EDP + j] = ac1[s];
        }
      }
      __syncthreads();
      if (!hv) {
#pragma unroll
        for (int s = 0; s < 20; ++s) {
          s_eq[s * EDP + j]        = (ac0[s] + s_eq[s * EDP + j])        + s_bql[j];
          s_eq[(20 + s) * EDP + j] = (ac1[s] + s_eq[(20 + s) * EDP + j]) + s_bql[j];
        }
      }
      __syncthreads();
    }
  }

  // U[prow][nd]: R10's masked-rotation form (fixed trip count, unroll 4)
  {
    float* wU = ws_U + (size_t)bc * (NNODE * NNODE);
    for (int e = t; e < NNODE * NNODE; e += THREADS) {
      int nd = e / NNODE, prow = e - nd * NNODE;
      const float* qr = &s_eq[prow * EDP];
      const float* kr = &s_Kl[nd * EDP];
      float S[4];
#pragma unroll
      for (int p = 0; p < 4; ++p) {
        int rot = (4 * nd + p) & 31;
        float a = 0.f;
#pragma unroll 4
        for (int i2 = 0; i2 < 32; ++i2) {
          int h = p * 32 + ((i2 + rot) & 31);
          a = fmaf(s_vl[h], xla_tanh(qr[h] + kr[h]), a);
        }
        S[p] = a;
      }
      wU[prow * NNODE + nd] = (S[0] + S[1]) + (S[2] + S[3]);
    }
  }
}

// ============== K2b: serial tail, one 64-thread block per (b,ci) ===========
__global__ __launch_bounds__(64)
void low_tail_kernel(const float* __restrict__ original_data,
                     const float* __restrict__ low_mask,
                     const int* __restrict__ ws_cidx,
                     const float* __restrict__ ws_meta,
                     const float* __restrict__ ws_U,
                     const float* __restrict__ ws_gum,
                     float* __restrict__ ws_pts,
                     float* __restrict__ out) {
  const int bc = blockIdx.x;
  const int b  = bc / NCELL;
  const int t  = threadIdx.x;

  __shared__ float sU[NNODE * NNODE];
  __shared__ float sG[NNODE * NNODE];
  __shared__ float sc[NNODE][2];
  __shared__ int s_cidx;

  if (t == 0) s_cidx = ws_cidx[bc];
  __syncthreads();
  const int cidx = s_cidx;

  {
    const float4* u4 = reinterpret_cast<const float4*>(ws_U + (size_t)bc * 1600);
    const float4* g4 = reinterpret_cast<const float4*>(ws_gum + (size_t)bc * 1600);
    float4* su4 = reinterpret_cast<float4*>(sU);
    float4* sg4 = reinterpret_cast<float4*>(sG);
    for (int i = t; i < 400; i += 64) { su4[i] = u4[i]; sg4[i] = g4[i]; }
    for (int q = t; q < 80; q += 64)
      sc[q >> 1][q & 1] = original_data[(((size_t)b * NCELL + cidx) * NNODE) * 2 + q];
  }
  float4 meta = reinterpret_cast<const float4*>(ws_meta)[bc];
  int   prev  = (int)meta.w;
  float initx = meta.x, inity = meta.y;
  float llp   = meta.z;
  float prevx = initx, prevy = inity, rew = 0.f;
  float maskreg = (t < NNODE) ? low_mask[b * NNODE + t] : 1.0f;
  if (t == prev) maskreg = 1.0f;
  __syncthreads();

  for (int st = 1; st < NNODE; ++st) {
    float logit = -__builtin_huge_valf(), val = -__builtin_huge_valf();
    if (t < NNODE) {
      float lg = (maskreg > 0.f) ? -1e9f : 10.0f * xla_tanh(sU[prev * NNODE + t]);
      logit = lg;
      val = lg + sG[st * NNODE + t];
    }
    int bidx = t;
    float mx = logit;
#pragma unroll
    for (int d = 32; d; d >>= 1) {
      float oval = __shfl_xor(val, d);
      int   oidx = __shfl_xor(bidx, d);
      float omx  = __shfl_xor(mx, d);
      if (oval > val || (oval == val && oidx < bidx)) { val = oval; bidx = oidx; }
      mx = fmaxf(mx, omx);
    }
    float ex = (t < NNODE) ? expf(logit - mx) : 0.f;
#pragma unroll
    for (int d = 32; d; d >>= 1) ex += __shfl_xor(ex, d);
    float chosen = __shfl(logit, bidx);
    llp += (chosen - mx) - logf(ex);
    float cx = sc[bidx][0], cy = sc[bidx][1];
    { float dx = cx - prevx, dy = cy - prevy; rew += sqrtf(dx * dx + dy * dy); }
    prevx = cx; prevy = cy;
    if (t == bidx) maskreg = 1.0f;
    prev = bidx;
    if (t == 0)
      out[OFF_NACT + ((size_t)bc) * NNODE + st] = (float)bidx;
  }
  if (t == 0) {
    out[OFF_NLP + bc] = llp;
    out[OFF_NRW + bc] = rew;
    float* p = ws_pts + (size_t)bc * 4;
    p[0] = initx; p[1] = inity; p[2] = prevx; p[3] = prevy;
  }
}

// ======== fallback: R8 fused low kernel (used if ws too small) =============
__global__ __launch_bounds__(THREADS, 2)
void low_kernel_fused(const float* __restrict__ node_context,
                      const float* __restrict__ original_data,
                      const float* __restrict__ low_mask,
                      const float* __restrict__ low_init_w,
                      const float* __restrict__ low_W_hc, const float* __restrict__ low_b_hc,
                      const float* __restrict__ low_W_vw, const float* __restrict__ low_b_vw,
                      const float* __restrict__ low_Wq,   const float* __restrict__ low_bq,
                      const float* __restrict__ low_Wk,   const float* __restrict__ low_bk,
                      const float* __restrict__ v_lo,
                      const int* __restrict__ ws_cidx,
                      float* __restrict__ ws_pts,
                      float* __restrict__ out) {
  const int bc = blockIdx.x;
  const int b  = bc / NCELL;
  const int ci = bc - b * NCELL;
  const int t  = threadIdx.x;
  const int j  = t & 127;
  const int hv = t >> 7;

  __shared__ float s_eq[NNODE * EDP];
  __shared__ float s_Kl[NNODE * EDP];
  __shared__ float s_U[NNODE * NNODE];
  __shared__ float s_gum[NNODE * NNODE];
  __shared__ float s_coords[NNODE][2];
  __shared__ float s_ql[EDIM], s_qq[EDIM], s_qbl[EDIM], s_hbl[EDIM];
  __shared__ float s_mean[EDIM], s_part[EDIM];
  __shared__ float s_vl[EDIM], s_bql[EDIM];
  __shared__ float s_iwl[2 * EDIM];
  __shared__ float s_u[NNODE];
  __shared__ float s_maskl[NNODE];
  __shared__ uint32_t s_ks[NNODE][2];
  __shared__ uint32_t s_kk[2];
  __shared__ int s_cidx;
  __shared__ int s_idx;

  if (t == 0) {
    uint32_t a0, a1, c0, c1;
    tf2x32(0u, 42u, 0u, 1u, a0, a1);
    tf2x32(a0, a1, 0u, (uint32_t)ci, c0, c1);
    s_kk[0] = c0; s_kk[1] = c1;
    s_cidx = ws_cidx[bc];
  }
  __syncthreads();
  const int cidx = s_cidx;

  if (t < EDIM) { s_vl[t] = v_lo[t]; s_bql[t] = low_bq[t]; }
  s_iwl[t] = low_init_w[t];
  if (t < NNODE)
    tf2x32(s_kk[0], s_kk[1], 0u, (uint32_t)t, s_ks[t][0], s_ks[t][1]);

  const float* embg = node_context + (((size_t)b * NCELL + cidx) * NNODE) * EDIM;
  if (t < EDIM) {
    float s = 0.f;
    for (int n = 0; n < NNODE; ++n) {
      float x = embg[n * EDIM + t];
      s_eq[n * EDP + t] = x; s += x;
    }
    s_mean[t] = s / 40.0f;
  }
  if (t >= 128 && t < 208) {
    int q = t - 128;
    s_coords[q >> 1][q & 1] = original_data[(((size_t)b * NCELL + cidx) * NNODE) * 2 + q];
  }
  if (t >= 208 && t < 208 + NNODE) s_maskl[t - 208] = low_mask[b * NNODE + (t - 208)];
  __syncthreads();

  for (int g = t; g < NNODE * NNODE; g += THREADS) {
    int st = g / NNODE, n = g - st * NNODE;
    s_gum[g] = bits_to_gumbel(draw_bits(s_ks[st][0], s_ks[st][1],
                                        (uint32_t)(b * NNODE + n)));
  }
  matvec<128>(low_W_hc, s_mean, nullptr, low_b_hc, s_hbl, s_part, t);
  computeK<20, EDP, EDP>(low_Wk, low_bk, &s_eq[0], &s_Kl[0], t);

  {
    float accA[20], accB[20];
#pragma unroll
    for (int s = 0; s < 20; ++s) { accA[s] = 0.f; accB[s] = 0.f; }
    const float* Wb = low_W_vw + (size_t)128 * EDIM + j;
#pragma unroll 2
    for (int k = 0; k < 64; ++k) {
      float w = Wb[(size_t)k * EDIM];
#pragma unroll
      for (int s = 0; s < 20; ++s)
        accA[s] = fmaf(s_eq[(hv + 2 * s) * EDP + k], w, accA[s]);
    }
#pragma unroll 2
    for (int k = 64; k < 128; ++k) {
      float w = Wb[(size_t)k * EDIM];
#pragma unroll
      for (int s = 0; s < 20; ++s)
        accB[s] = fmaf(s_eq[(hv + 2 * s) * EDP + k], w, accB[s]);
    }
    __syncthreads();
#pragma unroll
    for (int s = 0; s < 20; ++s)
      s_eq[(hv + 2 * s) * EDP + j] = accA[s] + accB[s];
  }
  matvec<256>(low_W_vw, s_iwl, s_hbl, low_b_vw, s_ql, s_part, t);
  if (t < EDIM) s_qbl[t] = s_hbl[t] + low_b_vw[t];
  __syncthreads();

  matvec<128>(low_Wq, s_ql, nullptr, s_bql, s_qq, s_part, t);
  if (t < 160) {
    int nd = t >> 2, p = t & 3, rot = t & 31;
    float acc = 0.f;
#pragma unroll 4
    for (int i2 = 0; i2 < 32; ++i2) {
      int h = p * 32 + ((i2 + rot) & 31);
      acc = fmaf(s_vl[h], xla_tanh(s_qq[h] + s_Kl[nd * EDP + h]), acc);
    }
    acc += __shfl_xor(acc, 1);
    acc += __shfl_xor(acc, 2);
    if (p == 0) s_u[nd] = acc;
  }
  __syncthreads();

  float llp = 0.f, rew = 0.f, prevx = 0.f, prevy = 0.f, initx = 0.f, inity = 0.f;
  float maskreg = 1.0f;
  int prev = 0;
  if (t < 64) {
    maskreg = (t < NNODE) ? s_maskl[t] : 1.0f;
    float logit = -__builtin_huge_valf(), val = -__builtin_huge_valf();
    if (t < NNODE) {
      float lg = (maskreg > 0.f) ? -1e9f : 10.0f * xla_tanh(s_u[t]);
      logit = lg;
      val = lg + s_gum[t];
    }
    int bidx = t;
    float mx = logit;
#pragma unroll
    for (int d = 32; d; d >>= 1) {
      float oval = __shfl_xor(val, d);
      int   oidx = __shfl_xor(bidx, d);
      float omx  = __shfl_xor(mx, d);
      if (oval > val || (oval == val && oidx < bidx)) { val = oval; bidx = oidx; }
      mx = fmaxf(mx, omx);
    }
    float ex = (t < NNODE) ? expf(logit - mx) : 0.f;
#pragma unroll
    for (int d = 32; d; d >>= 1) ex += __shfl_xor(ex, d);
    float chosen = __shfl(logit, bidx);
    llp += (chosen - mx) - logf(ex);
    initx = s_coords[bidx][0]; inity = s_coords[bidx][1];
    prevx = initx; prevy = inity;
    if (t == bidx) maskreg = 1.0f;
    prev = bidx;
    if (t == 0) {
      s_idx = bidx;
      out[OFF_NACT + ((size_t)bc) * NNODE + 0] = (float)bidx;
    }
  }
  __syncthreads();

  {
    const int n0 = s_idx;
    matvec<128>(low_W_vw, embg + (size_t)n0 * EDIM, s_qbl, nullptr, s_qbl, s_part, t);
    for (int i = t; i < NNODE * EDIM; i += THREADS) {
      int n = i >> 7, k = i & 127;
      s_eq[n * EDP + k] = s_eq[n * EDP + k] + s_qbl[k];
    }
    __syncthreads();
    {
      float ac0[20], ac1[20];
#pragma unroll
      for (int s = 0; s < 20; ++s) { ac0[s] = 0.f; ac1[s] = 0.f; }
      const float* Wqp = low_Wq + (size_t)(hv * 64) * EDIM + j;
      const float* qlb = &s_eq[0] + hv * 64;
#pragma unroll 2
      for (int k = 0; k < 64; ++k) {
        float w = Wqp[(size_t)k * EDIM];
#pragma unroll
        for (int s = 0; s < 20; ++s)
          ac0[s] = fmaf(qlb[s * EDP + k], w, ac0[s]);
#pragma unroll
        for (int s = 0; s < 20; ++s)
          ac1[s] = fmaf(qlb[(20 + s) * EDP + k], w, ac1[s]);
      }
      __syncthreads();
      if (hv) {
#pragma unroll
        for (int s = 0; s < 20; ++s) {
          s_eq[s * EDP + j]        = ac0[s];
          s_eq[(20 + s) * EDP + j] = ac1[s];
        }
      }
      __syncthreads();
      if (!hv) {
#pragma unroll
        for (int s = 0; s < 20; ++s) {
          s_eq[s * EDP + j]        = (ac0[s] + s_eq[s * EDP + j])        + s_bql[j];
          s_eq[(20 + s) * EDP + j] = (ac1[s] + s_eq[(20 + s) * EDP + j]) + s_bql[j];
        }
      }
      __syncthreads();
    }
  }

  for (int e = t; e < NNODE * NNODE; e += THREADS) {
    int nd = e / NNODE, prow = e - nd * NNODE;
    const float* qr = &s_eq[prow * EDP];
    const float* kr = &s_Kl[nd * EDP];
    float S[4];
#pragma unroll
    for (int p = 0; p < 4; ++p) {
      int rot = (4 * nd + p) & 31;
      float a = 0.f;
#pragma unroll 4
      for (int i2 = 0; i2 < 32; ++i2) {
        int h = p * 32 + ((i2 + rot) & 31);
        a = fmaf(s_vl[h], xla_tanh(qr[h] + kr[h]), a);
      }
      S[p] = a;
    }
    s_U[prow * NNODE + nd] = (S[0] + S[1]) + (S[2] + S[3]);
  }
  __syncthreads();

  if (t < 64) {
    for (int st = 1; st < NNODE; ++st) {
      float logit = -__builtin_huge_valf(), val = -__builtin_huge_valf();
      if (t < NNODE) {
        float lg = (maskreg > 0.f) ? -1e9f : 10.0f * xla_tanh(s_U[prev * NNODE + t]);
        logit = lg;
        val = lg + s_gum[st * NNODE + t];
      }
      int bidx = t;
      float mx = logit;
#pragma unroll
      for (int d = 32; d; d >>= 1) {
        float oval = __shfl_xor(val, d);
        int   oidx = __shfl_xor(bidx, d);
        float omx  = __shfl_xor(mx, d);
        if (oval > val || (oval == val && oidx < bidx)) { val = oval; bidx = oidx; }
        mx = fmaxf(mx, omx);
      }
      float ex = (t < NNODE) ? expf(logit - mx) : 0.f;
#pragma unroll
      for (int d = 32; d; d >>= 1) ex += __shfl_xor(ex, d);
      float chosen = __shfl(logit, bidx);
      llp += (chosen - mx) - logf(ex);
      float cx = s_coords[bidx][0], cy = s_coords[bidx][1];
      { float dx = cx - prevx, dy = cy - prevy; rew += sqrtf(dx * dx + dy * dy); }
      prevx = cx; prevy = cy;
      if (t == bidx) maskreg = 1.0f;
      prev = bidx;
      if (t == 0)
        out[OFF_NACT + ((size_t)bc) * NNODE + st] = (float)bidx;
    }
    if (t == 0) {
      out[OFF_NLP + bc] = llp;
      out[OFF_NRW + bc] = rew;
      float* p = ws_pts + (size_t)bc * 4;
      p[0] = initx; p[1] = inity; p[2] = prevx; p[3] = prevy;
    }
  }
}

// ======================= K3: cell_reward link =======================
__global__ void link_kernel(const float* __restrict__ ws_pts,
                            float* __restrict__ out) {
  int b = blockIdx.x * blockDim.x + threadIdx.x;
  if (b >= NB) return;
  float crew = 0.f;
  for (int ci = 1; ci < NCELL; ++ci) {
    const float* cur = ws_pts + (size_t)(b * NCELL + ci) * 4;
    const float* prv = ws_pts + (size_t)(b * NCELL + ci - 1) * 4;
    float dx = cur[0] - prv[2], dy = cur[1] - prv[3];
    crew += sqrtf(dx * dx + dy * dy);
  }
  out[OFF_CRW + b] = crew;
}

extern "C" void kernel_launch(void* const* d_in, const int* in_sizes, int n_in,
                              void* d_out, int out_size, void* d_ws, size_t ws_size,
                              hipStream_t stream) {
  (void)in_sizes; (void)n_in; (void)out_size;
  const float* node_context  = (const float*)d_in[0];
  const float* cell_context  = (const float*)d_in[1];
  const float* original_data = (const float*)d_in[2];
  const float* high_mask     = (const float*)d_in[3];
  const float* low_mask      = (const float*)d_in[4];
  const float* init_w        = (const float*)d_in[5];
  const float* W_hc  = (const float*)d_in[6];
  const float* b_hc  = (const float*)d_in[7];
  const float* W_vw  = (const float*)d_in[8];
  const float* b_vw  = (const float*)d_in[9];
  const float* Wq    = (const float*)d_in[10];
  const float* bq    = (const float*)d_in[11];
  const float* Wk    = (const float*)d_in[12];
  const float* bk    = (const float*)d_in[13];
  const float* v_hi  = (const float*)d_in[14];
  const float* low_init_w = (const float*)d_in[15];
  const float* low_W_hc   = (const float*)d_in[16];
  const float* low_b_hc   = (const float*)d_in[17];
  const float* low_W_vw   = (const float*)d_in[18];
  const float* low_b_vw   = (const float*)d_in[19];
  const float* low_Wq     = (const float*)d_in[20];
  const float* low_bq     = (const float*)d_in[21];
  const float* low_Wk     = (const float*)d_in[22];
  const float* low_bk     = (const float*)d_in[23];
  const float* v_lo       = (const float*)d_in[24];
  float* out = (float*)d_out;
  float* wsf = (float*)d_ws;
  int*   ws_cidx = (int*)d_ws;
  float* ws_pts  = wsf + WS_PTS_BASE;
  float* ws_meta = wsf + WS_META_BASE;
  float* ws_U    = wsf + WS_U_BASE;
  float* ws_gum  = wsf + WS_GUM_BASE;

  const bool big_ws = (ws_size >= WS_TOTAL_F * 4ull);

  high_kernel<<<big_ws ? (NB + NB * NCELL) : NB, THREADS, 0, stream>>>(
      cell_context, high_mask, init_w, W_hc, b_hc, W_vw, b_vw,
      Wq, bq, Wk, bk, v_hi, out, ws_cidx, ws_gum);

  if (big_ws) {
    low_pre_kernel<<<NB * NCELL, THREADS, 0, stream>>>(
        node_context, original_data, low_mask, low_init_w,
        low_W_hc, low_b_hc, low_W_vw, low_b_vw,
        low_Wq, low_bq, low_Wk, low_bk, v_lo,
        ws_cidx, ws_meta, ws_U, ws_gum, out);
    low_tail_kernel<<<NB * NCELL, 64, 0, stream>>>(
        original_data, low_mask, ws_cidx, ws_meta, ws_U, ws_gum, ws_pts, out);
  } else {
    low_kernel_fused<<<NB * NCELL, THREADS, 0, stream>>>(
        node_context, original_data, low_mask, low_init_w,
        low_W_hc, low_b_hc, low_W_vw, low_b_vw,
        low_Wq, low_bq, low_Wk, low_bk, v_lo,
        ws_cidx, ws_pts, out);
  }

  link_kernel<<<2, 256, 0, stream>>>(ws_pts, out);
}